// Round 1
// 1335.971 us; speedup vs baseline: 1.1491x; 1.1491x over previous
//
#include <hip/hip_runtime.h>
#include <cstdint>
#include <cstddef>

// Problem constants (fixed by setup_inputs; groupsize==256 is d_in[4] scalar)
#define M_TOK 8192        // B*S = 4*2048 tokens
#define K_IN  4096        // IN
#define N_OUT 11008       // OUT
#define GRP   256
#define NGRP  (K_IN / GRP)   // 16
#define NT_K  (K_IN / 64)    // 64 K-tiles of BK=64

typedef float f32x4   __attribute__((ext_vector_type(4)));
typedef short bf16x8  __attribute__((ext_vector_type(8)));  // 8 bf16 = 4 VGPRs

// fp32 -> bf16 round-to-nearest-even (no NaN inputs here)
__device__ inline unsigned short f2bf(float f) {
    uint32_t u = __float_as_uint(f);
    uint32_t r = (u + 0x7fffu + ((u >> 16) & 1u)) >> 16;
    return (unsigned short)r;
}

// ---------------------------------------------------------------------------
// Kernel 1: per-token dynamic int8 fake-quant -> bf16, bit-exact to reference
// ---------------------------------------------------------------------------
__global__ __launch_bounds__(256)
void quant_kernel(const float* __restrict__ x, unsigned short* __restrict__ qx)
{
    const int t   = blockIdx.x;
    const int tid = threadIdx.x;
    const float* xr = x + (size_t)t * K_IN;

    float4 v[4];
    float mn = 0.0f, mx = 0.0f;   // init 0 implements min(.,0)/max(.,0)
    #pragma unroll
    for (int j = 0; j < 4; ++j) {
        v[j] = ((const float4*)xr)[j * 256 + tid];
        mn = fminf(mn, fminf(fminf(v[j].x, v[j].y), fminf(v[j].z, v[j].w)));
        mx = fmaxf(mx, fmaxf(fmaxf(v[j].x, v[j].y), fmaxf(v[j].z, v[j].w)));
    }
    #pragma unroll
    for (int off = 32; off > 0; off >>= 1) {
        mn = fminf(mn, __shfl_xor(mn, off));
        mx = fmaxf(mx, __shfl_xor(mx, off));
    }
    __shared__ float smn[4], smx[4];
    if ((tid & 63) == 0) { smn[tid >> 6] = mn; smx[tid >> 6] = mx; }
    __syncthreads();
    mn = fminf(fminf(smn[0], smn[1]), fminf(smn[2], smn[3]));
    mx = fmaxf(fmaxf(smx[0], smx[1]), fmaxf(smx[2], smx[3]));

    const float scale = fmaxf((mx - mn) / 255.0f, 1.1920929e-7f);  // FLT_EPSILON
    const float dmin  = mn / scale;
    const float dmax  = mx / scale;
    float zp = (((-128.0f + dmin) + (127.0f + dmax)) > 0.0f) ? (-128.0f - dmin)
                                                             : (127.0f - dmax);
    zp = rintf(fminf(fmaxf(zp, -128.0f), 127.0f));

    unsigned short* qr = qx + (size_t)t * K_IN;
    #pragma unroll
    for (int j = 0; j < 4; ++j) {
        float q0 = fminf(fmaxf(rintf(v[j].x / scale) + zp, -128.0f), 127.0f);
        float q1 = fminf(fmaxf(rintf(v[j].y / scale) + zp, -128.0f), 127.0f);
        float q2 = fminf(fmaxf(rintf(v[j].z / scale) + zp, -128.0f), 127.0f);
        float q3 = fminf(fmaxf(rintf(v[j].w / scale) + zp, -128.0f), 127.0f);
        ushort4 o;
        o.x = f2bf((q0 - zp) * scale);
        o.y = f2bf((q1 - zp) * scale);
        o.z = f2bf((q2 - zp) * scale);
        o.w = f2bf((q3 - zp) * scale);
        ((ushort4*)qr)[j * 256 + tid] = o;
    }
}

// ---------------------------------------------------------------------------
// Kernel 2: groupwise int4 dequant of weights -> bf16, [N,K] row-major (B^T).
// ---------------------------------------------------------------------------
__global__ __launch_bounds__(256)
void wprep_kernel(const int* __restrict__ w, const float* __restrict__ scales,
                  const float* __restrict__ zeros, unsigned short* __restrict__ wdq)
{
    const size_t idx  = (size_t)blockIdx.x * 256 + threadIdx.x;
    const size_t base = idx * 4;                       // element index
    const int o = (int)(base >> 12);                   // /4096
    const int k = (int)(base & 4095);
    const int g = k >> 8;                              // /GRP
    const float s = scales[o * NGRP + g];
    const float z = zeros [o * NGRP + g];
    const int4 wi = *(const int4*)(w + base);
    ushort4 out;
    out.x = f2bf(((float)wi.x - z) * s);
    out.y = f2bf(((float)wi.y - z) * s);
    out.z = f2bf(((float)wi.z - z) * s);
    out.w = f2bf(((float)wi.w - z) * s);
    *(ushort4*)(wdq + base) = out;
}

// ---------------------------------------------------------------------------
// Kernel 3: bf16 GEMM, 256x256 tile, BK=64, 8-wave (2Mx4N), 8-phase schedule
// (T3+T4 counted vmcnt, T5 setprio, T1 XCD swizzle). C[M,N] = A[M,K]*B[N,K]^T.
//
// LDS: As[buf][mhalf][128][64], Bs[buf][nhalf][128][64] (128 KiB total).
//   A mhalf h packs rows {wr*128 + h*64 + r} at local row lr = wr*64 + r.
//   B nhalf h packs rows {wc*64  + h*32 + r} at local row lr = wc*32 + r.
//   Each half = 16 KiB = 2 global_load_lds issues (512 thr x 16B, linear dest).
//   XOR swizzle (proven 0-conflict in prior kernel): LDS chunk (lr, cc) holds
//   global k-chunk cc ^ (lr&7); reads XOR back. lr&7 == lrow&7 on both sides.
//
// Per K-tile: 4 phases, quadrant order (mh,nh) = (0,0),(0,1),(1,1),(1,0);
// 16 MFMA each; A-frags loaded at ph1/ph3 and reused at ph2/ph4 (ds_reads per
// phase: 12/4/8/4). Stage issues: ph1 -> B0(t+1) [into buf^1], ph2 -> A0(t+2),
// ph3 -> B1(t+2), ph4 -> A1(t+2) [into buf]; each region is restaged exactly
// one barrier after its last LDS read. Single s_waitcnt vmcnt(6) per K-tile at
// ph4: the 6 newest loads are the three t+2 half-tiles, so all of tile t+1 has
// landed while 3 half-tiles stay in flight across the barrier (never drain to
// 0 in the main loop; vmcnt(0) only at t = NT-2). Raw s_barrier throughout --
// __syncthreads would emit the draining vmcnt(0).
// ---------------------------------------------------------------------------

#define PH_SYNC_IN()  do { __builtin_amdgcn_sched_barrier(0); \
                           __builtin_amdgcn_s_barrier(); \
                           asm volatile("s_waitcnt lgkmcnt(0)" ::: "memory"); \
                           __builtin_amdgcn_sched_barrier(0); } while (0)
#define PH_SYNC_OUT() do { __builtin_amdgcn_sched_barrier(0); \
                           __builtin_amdgcn_s_barrier(); } while (0)

__device__ __forceinline__ void stage_a_half(unsigned short* dst,
                                             const unsigned short* __restrict__ A,
                                             int bm, int k0, int half, int tid)
{
    #pragma unroll
    for (int i = 0; i < 2; ++i) {
        const int c  = i * 512 + tid;                 // 16B chunk id in 16 KiB half
        const int lr = c >> 3;                        // local row 0..127
        const int cc = c & 7;                         // LDS k-chunk
        const int gc = cc ^ (lr & 7);                 // global k-chunk (swizzle)
        const int gr = ((lr >> 6) << 7) + (half << 6) + (lr & 63); // wr*128+h*64+r
        __builtin_amdgcn_global_load_lds(
            (const __attribute__((address_space(1))) void*)(A + (size_t)(bm + gr) * K_IN + k0 + (gc << 3)),
            (__attribute__((address_space(3))) void*)(dst + (size_t)c * 8),
            16, 0, 0);
    }
}

__device__ __forceinline__ void stage_b_half(unsigned short* dst,
                                             const unsigned short* __restrict__ B,
                                             int bn, int k0, int half, int tid)
{
    #pragma unroll
    for (int i = 0; i < 2; ++i) {
        const int c  = i * 512 + tid;
        const int lr = c >> 3;
        const int cc = c & 7;
        const int gc = cc ^ (lr & 7);
        const int gr = ((lr >> 5) << 6) + (half << 5) + (lr & 31); // wc*64+h*32+r
        __builtin_amdgcn_global_load_lds(
            (const __attribute__((address_space(1))) void*)(B + (size_t)(bn + gr) * K_IN + k0 + (gc << 3)),
            (__attribute__((address_space(3))) void*)(dst + (size_t)c * 8),
            16, 0, 0);
    }
}

__device__ __forceinline__ void ld_afrag(bf16x8 (&a)[4][2], const unsigned short* Ah,
                                         int wr, int lrow, int khi)
{
    #pragma unroll
    for (int mi = 0; mi < 4; ++mi) {
        const int lr = wr * 64 + mi * 16 + lrow;
        #pragma unroll
        for (int kk = 0; kk < 2; ++kk) {
            const int sc = (kk * 4 + khi) ^ (lr & 7);
            a[mi][kk] = *(const bf16x8*)(Ah + lr * 64 + sc * 8);
        }
    }
}

__device__ __forceinline__ void ld_bfrag(bf16x8 (&b)[2][2], const unsigned short* Bh,
                                         int wc, int lrow, int khi)
{
    #pragma unroll
    for (int ni = 0; ni < 2; ++ni) {
        const int lr = wc * 32 + ni * 16 + lrow;
        #pragma unroll
        for (int kk = 0; kk < 2; ++kk) {
            const int sc = (kk * 4 + khi) ^ (lr & 7);
            b[ni][kk] = *(const bf16x8*)(Bh + lr * 64 + sc * 8);
        }
    }
}

template<int MH, int NH>
__device__ __forceinline__ void mfma_quad(f32x4 (&acc)[8][4],
                                          const bf16x8 (&a)[4][2],
                                          const bf16x8 (&b)[2][2])
{
    __builtin_amdgcn_s_setprio(1);
    #pragma unroll
    for (int kk = 0; kk < 2; ++kk)
        #pragma unroll
        for (int mi = 0; mi < 4; ++mi)
            #pragma unroll
            for (int ni = 0; ni < 2; ++ni)
                acc[MH * 4 + mi][NH * 2 + ni] =
                    __builtin_amdgcn_mfma_f32_16x16x32_bf16(
                        a[mi][kk], b[ni][kk], acc[MH * 4 + mi][NH * 2 + ni], 0, 0, 0);
    __builtin_amdgcn_s_setprio(0);
}

__global__ __launch_bounds__(512, 2)
void gemm_kernel(const unsigned short* __restrict__ A,   // [M_TOK, K_IN] bf16
                 const unsigned short* __restrict__ B,   // [N_OUT, K_IN] bf16
                 float* __restrict__ C)                  // [M_TOK, N_OUT] f32
{
    __shared__ unsigned short As[2][2][128 * 64];  // [buf][mhalf] 64 KiB
    __shared__ unsigned short Bs[2][2][128 * 64];  // [buf][nhalf] 64 KiB

    const int tid  = threadIdx.x;
    const int lane = tid & 63;
    const int wave = tid >> 6;
    const int wr   = wave >> 2;          // 0..1  (M half of tile, 128 rows)
    const int wc   = wave & 3;           // 0..3  (N quarter of tile, 64 cols)
    const int lrow = lane & 15;
    const int khi  = lane >> 4;          // 0..3

    // T1: XCD-aware swizzle; grid = 43*32 = 1376 = 8*172 (bijective)
    const int bid = blockIdx.x;
    const int swz = (bid & 7) * 172 + (bid >> 3);
    const int bm  = (swz / 43) * 256;
    const int bn  = (swz % 43) * 256;

    // Prologue: tile 0 complete (buf0) + tile 1 {A0, B1, A1} (buf1).
    // B0(t1) is staged at t0.ph1, matching the steady-state issue pattern.
    stage_a_half(&As[0][0][0], A, bm, 0, 0, tid);
    stage_b_half(&Bs[0][0][0], B, bn, 0, 0, tid);
    stage_a_half(&As[0][1][0], A, bm, 0, 1, tid);
    stage_b_half(&Bs[0][1][0], B, bn, 0, 1, tid);
    stage_a_half(&As[1][0][0], A, bm, 64, 0, tid);
    stage_b_half(&Bs[1][1][0], B, bn, 64, 1, tid);
    stage_a_half(&As[1][1][0], A, bm, 64, 1, tid);
    asm volatile("s_waitcnt vmcnt(6)" ::: "memory");   // tile0's 8 loads landed
    __builtin_amdgcn_sched_barrier(0);
    __builtin_amdgcn_s_barrier();

    f32x4 acc[8][4] = {};
    int buf = 0;

    for (int t = 0; t < NT_K; ++t) {
        const int k1 = (t + 1) << 6;
        const int k2 = (t + 2) << 6;
        const bool p1 = t < NT_K - 1;
        const bool p2 = t < NT_K - 2;
        bf16x8 a[4][2], b[2][2];

        // ---- phase 1: quadrant (mh0, nh0); stage B0(t+1) -> buf^1
        ld_afrag(a, &As[buf][0][0], wr, lrow, khi);
        ld_bfrag(b, &Bs[buf][0][0], wc, lrow, khi);
        if (p1) stage_b_half(&Bs[buf ^ 1][0][0], B, bn, k1, 0, tid);
        PH_SYNC_IN();
        mfma_quad<0, 0>(acc, a, b);
        PH_SYNC_OUT();

        // ---- phase 2: (mh0, nh1); A-frags reused; stage A0(t+2) -> buf
        ld_bfrag(b, &Bs[buf][1][0], wc, lrow, khi);
        if (p2) stage_a_half(&As[buf][0][0], A, bm, k2, 0, tid);
        PH_SYNC_IN();
        mfma_quad<0, 1>(acc, a, b);
        PH_SYNC_OUT();

        // ---- phase 3: (mh1, nh1); B-frags reused; stage B1(t+2) -> buf
        ld_afrag(a, &As[buf][1][0], wr, lrow, khi);
        if (p2) stage_b_half(&Bs[buf][1][0], B, bn, k2, 1, tid);
        PH_SYNC_IN();
        mfma_quad<1, 1>(acc, a, b);
        PH_SYNC_OUT();

        // ---- phase 4: (mh1, nh0); re-read B0; stage A1(t+2) -> buf
        ld_bfrag(b, &Bs[buf][0][0], wc, lrow, khi);
        if (p2) stage_a_half(&As[buf][1][0], A, bm, k2, 1, tid);
        // Counted wait: 6 newest = A0/B1/A1(t+2) may stay in flight; everything
        // tile t+1 needs (issued <= this tile's ph1) is forced to land.
        if (p2)      { asm volatile("s_waitcnt vmcnt(6)" ::: "memory"); }
        else if (p1) { asm volatile("s_waitcnt vmcnt(0)" ::: "memory"); }
        PH_SYNC_IN();
        mfma_quad<1, 0>(acc, a, b);
        PH_SYNC_OUT();

        buf ^= 1;
    }

    // Epilogue: C/D layout (verified m89/m91): col = lane&15, row = (lane>>4)*4 + reg
    const int crow = khi * 4;
    #pragma unroll
    for (int mi = 0; mi < 8; ++mi) {
        #pragma unroll
        for (int ni = 0; ni < 4; ++ni) {
            const f32x4 v = acc[mi][ni];
            const int m0 = bm + wr * 128 + mi * 16 + crow;
            const int n0 = bn + wc * 64 + ni * 16 + lrow;
            #pragma unroll
            for (int r = 0; r < 4; ++r)
                C[(size_t)(m0 + r) * N_OUT + n0] = v[r];
        }
    }
}

// ---------------------------------------------------------------------------
extern "C" void kernel_launch(void* const* d_in, const int* in_sizes, int n_in,
                              void* d_out, int out_size, void* d_ws, size_t ws_size,
                              hipStream_t stream)
{
    const float* x      = (const float*)d_in[0];  // [4,2048,4096] f32
    const int*   w      = (const int*)  d_in[1];  // [11008,4096] int32 in [-8,7]
    const float* scales = (const float*)d_in[2];  // [11008,16] f32
    const float* zeros  = (const float*)d_in[3];  // [11008,16] f32
    float* out = (float*)d_out;                   // [8192,11008] f32

    unsigned short* qx  = (unsigned short*)d_ws;
    unsigned short* wdq = qx + (size_t)M_TOK * K_IN;

    quant_kernel<<<M_TOK, 256, 0, stream>>>(x, qx);
    wprep_kernel<<<(int)(((size_t)N_OUT * K_IN / 4) / 256), 256, 0, stream>>>(w, scales, zeros, wdq);
    gemm_kernel<<<1376, 512, 0, stream>>>(qx, wdq, out);
}